// Round 1
// baseline (13457.242 us; speedup 1.0000x reference)
//
#include <hip/hip_runtime.h>
#include <hip/hip_bf16.h>
#include <math.h>

#define B_   2
#define S_   2048
#define H_   2048
#define NH   16
#define HD   128
#define ROWS (B_ * S_)   // 4096
#define F3   (3 * H_)    // 6144

// ---------------------------------------------------------------------------
// fp8 e4m3fn round-to-nearest-even quantization, returning the representable
// VALUE (we never need the byte encoding; dequantized values are exact in bf16)
// ---------------------------------------------------------------------------
__device__ __forceinline__ float quant_e4m3(float x) {
  float ax = fabsf(x);
  float q;
  if (ax < 0.015625f) {                      // below min normal 2^-6: quantum 2^-9
    q = rintf(ax * 512.0f) * (1.0f / 512.0f);
  } else {
    unsigned eb = __float_as_uint(ax) & 0x7f800000u;       // exponent field
    float quantum = __uint_as_float(eb - (3u << 23));      // 2^(e-3): 3 mantissa bits
    q = rintf(ax / quantum) * quantum;                     // RNE (v_rndne_f32)
    if (q > 448.0f) q = 448.0f;                            // e4m3fn max
  }
  return copysignf(q, x);
}

// ---------------------------------------------------------------------------
// fp32 SGEMM: C[M,N] = A[M,K] @ B[K,N] (+ bias). 128x128 tile, BK=8,
// 256 threads, 8x8 per thread. M,N,K all multiples of 128/8 here.
// ---------------------------------------------------------------------------
__global__ __launch_bounds__(256) void sgemm128(
    const float* __restrict__ A, const float* __restrict__ Bm,
    float* __restrict__ C, const float* __restrict__ bias,
    int M, int N, int K, int has_bias) {
  __shared__ float As[8][128];
  __shared__ float Bs[8][128];
  const int t = threadIdx.x;
  const int tx = t & 15, ty = t >> 4;
  const int arow = t >> 1, acol = (t & 1) * 4;   // A tile: 128 rows x 8 k
  const int brow = t >> 5, bcol = (t & 31) * 4;  // B tile: 8 k x 128 cols
  const float* Ap = A + (size_t)(blockIdx.y * 128 + arow) * K + acol;
  const float* Bp = Bm + (size_t)brow * N + blockIdx.x * 128 + bcol;

  float acc[8][8];
#pragma unroll
  for (int i = 0; i < 8; i++)
#pragma unroll
    for (int j = 0; j < 8; j++) acc[i][j] = 0.0f;

  for (int k0 = 0; k0 < K; k0 += 8) {
    float4 av = *(const float4*)(Ap + k0);
    float4 bv = *(const float4*)(Bp + (size_t)k0 * N);
    __syncthreads();
    As[acol + 0][arow] = av.x;
    As[acol + 1][arow] = av.y;
    As[acol + 2][arow] = av.z;
    As[acol + 3][arow] = av.w;
    *(float4*)&Bs[brow][bcol] = bv;
    __syncthreads();
#pragma unroll
    for (int kk = 0; kk < 8; kk++) {
      float a[8], b[8];
      *(float4*)&a[0] = *(const float4*)&As[kk][ty * 8];
      *(float4*)&a[4] = *(const float4*)&As[kk][ty * 8 + 4];
      *(float4*)&b[0] = *(const float4*)&Bs[kk][tx * 8];
      *(float4*)&b[4] = *(const float4*)&Bs[kk][tx * 8 + 4];
#pragma unroll
      for (int i = 0; i < 8; i++)
#pragma unroll
        for (int j = 0; j < 8; j++)
          acc[i][j] = fmaf(a[i], b[j], acc[i][j]);
    }
  }

  const int crow = blockIdx.y * 128 + ty * 8;
  const int ccol = blockIdx.x * 128 + tx * 8;
#pragma unroll
  for (int i = 0; i < 8; i++) {
    float o[8];
#pragma unroll
    for (int j = 0; j < 8; j++) o[j] = acc[i][j];
    if (has_bias) {
#pragma unroll
      for (int j = 0; j < 8; j++) o[j] += bias[ccol + j];
    }
    *(float4*)(C + (size_t)(crow + i) * N + ccol) = *(float4*)&o[0];
    *(float4*)(C + (size_t)(crow + i) * N + ccol + 4) = *(float4*)&o[4];
  }
}

// ---------------------------------------------------------------------------
// Global max|.| over q / k / v segments of qkv. One block per (row, segment).
// Result as uint bit pattern (valid ordering for non-negative floats).
// ---------------------------------------------------------------------------
__global__ __launch_bounds__(256) void maxabs_kernel(
    const float* __restrict__ qkv, unsigned* __restrict__ mx) {
  __shared__ float red[256];
  const int seg = blockIdx.x % 3;
  const int row = blockIdx.x / 3;
  const float4* p = (const float4*)(qkv + (size_t)row * F3 + seg * 2048);
  float m = 0.0f;
  for (int i = threadIdx.x; i < 512; i += 256) {
    float4 v = p[i];
    m = fmaxf(m, fmaxf(fmaxf(fabsf(v.x), fabsf(v.y)), fmaxf(fabsf(v.z), fabsf(v.w))));
  }
  red[threadIdx.x] = m;
  __syncthreads();
  for (int s = 128; s > 0; s >>= 1) {
    if (threadIdx.x < s) red[threadIdx.x] = fmaxf(red[threadIdx.x], red[threadIdx.x + s]);
    __syncthreads();
  }
  if (threadIdx.x == 0) atomicMax(mx + seg, __float_as_uint(red[0]));
}

// ---------------------------------------------------------------------------
// Quantize qkv -> e4m3fn values, store dequantized (pre-scale) values as bf16
// in [b][head][s][d] layout per tensor. Matches ref: scale = max/448 (fp32 div),
// x/scale (fp32 div), RNE to e4m3.
// ---------------------------------------------------------------------------
__global__ __launch_bounds__(256) void quant_kernel(
    const float* __restrict__ qkv, const unsigned* __restrict__ mx,
    unsigned short* __restrict__ q8, unsigned short* __restrict__ k8,
    unsigned short* __restrict__ v8) {
  const size_t idx4 = (size_t)blockIdx.x * 256 + threadIdx.x;
  const size_t base = idx4 * 4;
  const int row = (int)(base / F3);
  const int col = (int)(base % F3);
  const int seg = col >> 11;        // 0:q 1:k 2:v
  const int c2 = col & 2047;
  const int h = c2 >> 7, d = c2 & 127;
  const int b = row >> 11, s = row & 2047;
  const float scale = __uint_as_float(mx[seg]) / 448.0f;
  float4 v = *(const float4*)(qkv + base);
  ushort4 rv;
  rv.x = (unsigned short)(__float_as_uint(quant_e4m3(v.x / scale)) >> 16);
  rv.y = (unsigned short)(__float_as_uint(quant_e4m3(v.y / scale)) >> 16);
  rv.z = (unsigned short)(__float_as_uint(quant_e4m3(v.z / scale)) >> 16);
  rv.w = (unsigned short)(__float_as_uint(quant_e4m3(v.w / scale)) >> 16);
  unsigned short* dst = (seg == 0) ? q8 : (seg == 1) ? k8 : v8;
  const size_t di = ((size_t)(b * NH + h) * S_ + s) * HD + d;  // d % 4 == 0
  *(ushort4*)(dst + di) = rv;
}

// ---------------------------------------------------------------------------
// Attention: one block (256 thr) per (b, head, query). Scores in LDS,
// two-pass softmax, PV with coalesced bf16-pair loads.
// out layout: [B,S,H] fp32 (already transposed back, heads side by side).
// ---------------------------------------------------------------------------
__global__ __launch_bounds__(256) void attn_kernel(
    const unsigned short* __restrict__ q8, const unsigned short* __restrict__ k8,
    const unsigned short* __restrict__ v8, const unsigned* __restrict__ mx,
    float* __restrict__ out) {
  __shared__ float sc[2048];
  __shared__ float qv[128];
  __shared__ float red[512];
  const int t = threadIdx.x;
  const int qi = blockIdx.x & (S_ - 1);
  const int bh = blockIdx.x >> 11;  // b*16 + h
  const unsigned short* Q = q8 + ((size_t)bh * S_ + qi) * HD;
  const unsigned short* K = k8 + (size_t)bh * S_ * HD;
  const unsigned short* V = v8 + (size_t)bh * S_ * HD;

  if (t < 64) {
    unsigned u = ((const unsigned*)Q)[t];
    qv[2 * t]     = __uint_as_float(u << 16);
    qv[2 * t + 1] = __uint_as_float(u & 0xffff0000u);
  }
  __syncthreads();
  const float qs = __uint_as_float(mx[0]) / 448.0f;
  const float ks = __uint_as_float(mx[1]) / 448.0f;
  const float vs = __uint_as_float(mx[2]) / 448.0f;
  const float sfac = qs * ks * 0.08838834764831843f;  // * 1/sqrt(128)

  // --- scores: each thread does keys j = t + 256*jj ---
  float dot[8];
#pragma unroll
  for (int jj = 0; jj < 8; jj++) dot[jj] = 0.0f;
  const uint4* Kb = (const uint4*)K;  // 16 uint4 per key row
#pragma unroll
  for (int c = 0; c < 16; c++) {
    float4 qa = *(const float4*)&qv[c * 8];
    float4 qb = *(const float4*)&qv[c * 8 + 4];
#pragma unroll
    for (int jj = 0; jj < 8; jj++) {
      const int j = t + jj * 256;
      uint4 u = Kb[(size_t)j * 16 + c];
      dot[jj] = fmaf(qa.x, __uint_as_float(u.x << 16), dot[jj]);
      dot[jj] = fmaf(qa.y, __uint_as_float(u.x & 0xffff0000u), dot[jj]);
      dot[jj] = fmaf(qa.z, __uint_as_float(u.y << 16), dot[jj]);
      dot[jj] = fmaf(qa.w, __uint_as_float(u.y & 0xffff0000u), dot[jj]);
      dot[jj] = fmaf(qb.x, __uint_as_float(u.z << 16), dot[jj]);
      dot[jj] = fmaf(qb.y, __uint_as_float(u.z & 0xffff0000u), dot[jj]);
      dot[jj] = fmaf(qb.z, __uint_as_float(u.w << 16), dot[jj]);
      dot[jj] = fmaf(qb.w, __uint_as_float(u.w & 0xffff0000u), dot[jj]);
    }
  }
  float lmax = -3.0e38f;
#pragma unroll
  for (int jj = 0; jj < 8; jj++) {
    float s = dot[jj] * sfac;
    sc[t + jj * 256] = s;
    lmax = fmaxf(lmax, s);
  }
  red[t] = lmax;
  __syncthreads();
  for (int s2 = 128; s2 > 0; s2 >>= 1) {
    if (t < s2) red[t] = fmaxf(red[t], red[t + s2]);
    __syncthreads();
  }
  const float m = red[0];
  __syncthreads();

  float lsum = 0.0f;
#pragma unroll
  for (int jj = 0; jj < 8; jj++) {
    const int j = t + jj * 256;
    float p = expf(sc[j] - m);
    sc[j] = p;
    lsum += p;
  }
  __syncthreads();
  red[t] = lsum;
  __syncthreads();
  for (int s2 = 128; s2 > 0; s2 >>= 1) {
    if (t < s2) red[t] += red[t + s2];
    __syncthreads();
  }
  const float l = red[0];
  __syncthreads();

  // --- PV: thread handles d pair (2*d2, 2*d2+1), j stride 4 ---
  const int d2 = t & 63;
  const int q4 = t >> 6;
  float a0 = 0.0f, a1 = 0.0f;
  const unsigned* Vw = (const unsigned*)V;
  for (int j = q4; j < S_; j += 4) {
    const float p = sc[j];
    unsigned u = Vw[(size_t)j * 64 + d2];
    a0 = fmaf(p, __uint_as_float(u << 16), a0);
    a1 = fmaf(p, __uint_as_float(u & 0xffff0000u), a1);
  }
  red[t] = a0;
  red[256 + t] = a1;
  __syncthreads();
  if (t < 64) {
    const float inv = vs / l;
    float o0 = (red[t] + red[64 + t] + red[128 + t] + red[192 + t]) * inv;
    float o1 = (red[256 + t] + red[320 + t] + red[384 + t] + red[448 + t]) * inv;
    const int b = bh >> 4, h = bh & 15;
    float2 o = make_float2(o0, o1);
    *(float2*)(out + ((size_t)(b * S_ + qi)) * H_ + h * HD + 2 * t) = o;
  }
}

// ---------------------------------------------------------------------------
extern "C" void kernel_launch(void* const* d_in, const int* in_sizes, int n_in,
                              void* d_out, int out_size, void* d_ws, size_t ws_size,
                              hipStream_t stream) {
  const float* x     = (const float*)d_in[0];  // [2,2048,2048]
  const float* W_qkv = (const float*)d_in[1];  // [2048,6144]
  const float* W_out = (const float*)d_in[2];  // [2048,2048]
  const float* b_out = (const float*)d_in[3];  // [2048]
  float* out = (float*)d_out;                  // [2,2048,2048]

  char* ws = (char*)d_ws;
  float* qkv            = (float*)ws;                          // 100,663,296 B
  unsigned short* q8    = (unsigned short*)(ws + 100663296);   // 16,777,216 B each
  unsigned short* k8    = (unsigned short*)(ws + 117440512);
  unsigned short* v8    = (unsigned short*)(ws + 134217728);
  unsigned* mx          = (unsigned*)(ws + 150994944);         // 3 x u32
  float* attn_out       = (float*)ws;  // reuse qkv region (dead after quant)

  hipMemsetAsync(mx, 0, 3 * sizeof(unsigned), stream);

  // 1) qkv = x @ W_qkv   (fp32)
  sgemm128<<<dim3(F3 / 128, ROWS / 128), 256, 0, stream>>>(
      x, W_qkv, qkv, nullptr, ROWS, F3, H_, 0);

  // 2) per-tensor max|.| for q, k, v
  maxabs_kernel<<<ROWS * 3, 256, 0, stream>>>(qkv, mx);

  // 3) quantize to e4m3fn values, store as exact bf16 in [b,h,s,d]
  quant_kernel<<<(ROWS * F3) / 1024, 256, 0, stream>>>(qkv, mx, q8, k8, v8);

  // 4) attention (scores -> softmax -> PV, * v_scale)
  attn_kernel<<<B_ * NH * S_, 256, 0, stream>>>(q8, k8, v8, mx, attn_out);

  // 5) out = attn_out @ W_out + b_out   (fp32)
  sgemm128<<<dim3(H_ / 128, ROWS / 128), 256, 0, stream>>>(
      attn_out, W_out, out, b_out, ROWS, H_, H_, 1);
}

// Round 2
// 2180.906 us; speedup vs baseline: 6.1705x; 6.1705x over previous
//
#include <hip/hip_runtime.h>
#include <hip/hip_bf16.h>
#include <math.h>

#define B_   2
#define S_   2048
#define H_   2048
#define NH   16
#define HD   128
#define ROWS (B_ * S_)   // 4096
#define F3   (3 * H_)    // 6144

typedef _Float16 f16x8 __attribute__((ext_vector_type(8)));
typedef float    f32x16 __attribute__((ext_vector_type(16)));

union H2 { unsigned u; _Float16 h[2]; };
union H4 { ushort4 s4; _Float16 h[4]; };

// ---------------------------------------------------------------------------
// fp8 e4m3fn RNE quantization -> representable value (exact in fp16)
// ---------------------------------------------------------------------------
__device__ __forceinline__ float quant_e4m3(float x) {
  float ax = fabsf(x);
  float q;
  if (ax < 0.015625f) {                      // below min normal 2^-6: quantum 2^-9
    q = rintf(ax * 512.0f) * (1.0f / 512.0f);
  } else {
    unsigned eb = __float_as_uint(ax) & 0x7f800000u;
    float quantum = __uint_as_float(eb - (3u << 23));      // 2^(e-3)
    q = rintf(ax / quantum) * quantum;
    if (q > 448.0f) q = 448.0f;
  }
  return copysignf(q, x);
}

// ---------------------------------------------------------------------------
// fp32 SGEMM (unchanged this round): C[M,N] = A @ B (+bias), 128x128 tile
// ---------------------------------------------------------------------------
__global__ __launch_bounds__(256) void sgemm128(
    const float* __restrict__ A, const float* __restrict__ Bm,
    float* __restrict__ C, const float* __restrict__ bias,
    int M, int N, int K, int has_bias) {
  __shared__ float As[8][128];
  __shared__ float Bs[8][128];
  const int t = threadIdx.x;
  const int tx = t & 15, ty = t >> 4;
  const int arow = t >> 1, acol = (t & 1) * 4;
  const int brow = t >> 5, bcol = (t & 31) * 4;
  const float* Ap = A + (size_t)(blockIdx.y * 128 + arow) * K + acol;
  const float* Bp = Bm + (size_t)brow * N + blockIdx.x * 128 + bcol;

  float acc[8][8];
#pragma unroll
  for (int i = 0; i < 8; i++)
#pragma unroll
    for (int j = 0; j < 8; j++) acc[i][j] = 0.0f;

  for (int k0 = 0; k0 < K; k0 += 8) {
    float4 av = *(const float4*)(Ap + k0);
    float4 bv = *(const float4*)(Bp + (size_t)k0 * N);
    __syncthreads();
    As[acol + 0][arow] = av.x;
    As[acol + 1][arow] = av.y;
    As[acol + 2][arow] = av.z;
    As[acol + 3][arow] = av.w;
    *(float4*)&Bs[brow][bcol] = bv;
    __syncthreads();
#pragma unroll
    for (int kk = 0; kk < 8; kk++) {
      float a[8], b[8];
      *(float4*)&a[0] = *(const float4*)&As[kk][ty * 8];
      *(float4*)&a[4] = *(const float4*)&As[kk][ty * 8 + 4];
      *(float4*)&b[0] = *(const float4*)&Bs[kk][tx * 8];
      *(float4*)&b[4] = *(const float4*)&Bs[kk][tx * 8 + 4];
#pragma unroll
      for (int i = 0; i < 8; i++)
#pragma unroll
        for (int j = 0; j < 8; j++)
          acc[i][j] = fmaf(a[i], b[j], acc[i][j]);
    }
  }

  const int crow = blockIdx.y * 128 + ty * 8;
  const int ccol = blockIdx.x * 128 + tx * 8;
#pragma unroll
  for (int i = 0; i < 8; i++) {
    float o[8];
#pragma unroll
    for (int j = 0; j < 8; j++) o[j] = acc[i][j];
    if (has_bias) {
#pragma unroll
      for (int j = 0; j < 8; j++) o[j] += bias[ccol + j];
    }
    *(float4*)(C + (size_t)(crow + i) * N + ccol) = *(float4*)&o[0];
    *(float4*)(C + (size_t)(crow + i) * N + ccol + 4) = *(float4*)&o[4];
  }
}

// ---------------------------------------------------------------------------
// Global max|.| per q/k/v segment
// ---------------------------------------------------------------------------
__global__ __launch_bounds__(256) void maxabs_kernel(
    const float* __restrict__ qkv, unsigned* __restrict__ mx) {
  __shared__ float red[256];
  const int seg = blockIdx.x % 3;
  const int row = blockIdx.x / 3;
  const float4* p = (const float4*)(qkv + (size_t)row * F3 + seg * 2048);
  float m = 0.0f;
  for (int i = threadIdx.x; i < 512; i += 256) {
    float4 v = p[i];
    m = fmaxf(m, fmaxf(fmaxf(fabsf(v.x), fabsf(v.y)), fmaxf(fabsf(v.z), fabsf(v.w))));
  }
  red[threadIdx.x] = m;
  __syncthreads();
  for (int s = 128; s > 0; s >>= 1) {
    if (threadIdx.x < s) red[threadIdx.x] = fmaxf(red[threadIdx.x], red[threadIdx.x + s]);
    __syncthreads();
  }
  if (threadIdx.x == 0) atomicMax(mx + seg, __float_as_uint(red[0]));
}

// ---------------------------------------------------------------------------
// Quantize Q,K segments (cols 0..4095) -> fp16 exact e4m3 values, [bh][s][d]
// ---------------------------------------------------------------------------
__global__ __launch_bounds__(256) void quant_qk(
    const float* __restrict__ qkv, const unsigned* __restrict__ mx,
    _Float16* __restrict__ q8, _Float16* __restrict__ k8) {
  const size_t base = ((size_t)blockIdx.x * 256 + threadIdx.x) * 4;
  const int row = (int)(base >> 12);        // 4096 q|k cols per row
  const int col = (int)(base & 4095);
  const int seg = col >> 11;
  const int c2 = col & 2047;
  const int h = c2 >> 7, d = c2 & 127;
  const int b = row >> 11, s = row & 2047;
  const float scale = __uint_as_float(mx[seg]) / 448.0f;
  float4 v = *(const float4*)(qkv + (size_t)row * F3 + col);
  H4 r;
  r.h[0] = (_Float16)quant_e4m3(v.x / scale);
  r.h[1] = (_Float16)quant_e4m3(v.y / scale);
  r.h[2] = (_Float16)quant_e4m3(v.z / scale);
  r.h[3] = (_Float16)quant_e4m3(v.w / scale);
  _Float16* dst = seg ? k8 : q8;
  const size_t di = ((size_t)((b * NH + h) * S_) + s) * HD + d;
  *(ushort4*)(dst + di) = r.s4;
}

// ---------------------------------------------------------------------------
// Quantize V segment -> fp16 values stored TRANSPOSED: v8t[bh][d][s]
// 64s x 64d tiles through LDS.
// ---------------------------------------------------------------------------
__global__ __launch_bounds__(256) void quant_v_t(
    const float* __restrict__ qkv, const unsigned* __restrict__ mx,
    _Float16* __restrict__ v8t) {
  __shared__ _Float16 tile[64 * 72];        // [d][s], stride 72 (144B, 16B-mult)
  const int t = threadIdx.x;
  const int bt = blockIdx.x;
  const int dtile = bt & 1;
  const int stile = (bt >> 1) & 31;
  const int bh = bt >> 6;
  const int b = bh >> 4, h = bh & 15;
  const int s0 = stile * 64, d0 = dtile * 64;
  const float scale = __uint_as_float(mx[2]) / 448.0f;

#pragma unroll
  for (int r = 0; r < 4; r++) {
    const int s = s0 + r * 16 + (t >> 4);
    const int dl = (t & 15) * 4;
    float4 v = *(const float4*)(qkv + (size_t)(b * S_ + s) * F3 + 4096 + h * HD + d0 + dl);
    tile[(dl + 0) * 72 + r * 16 + (t >> 4)] = (_Float16)quant_e4m3(v.x / scale);
    tile[(dl + 1) * 72 + r * 16 + (t >> 4)] = (_Float16)quant_e4m3(v.y / scale);
    tile[(dl + 2) * 72 + r * 16 + (t >> 4)] = (_Float16)quant_e4m3(v.z / scale);
    tile[(dl + 3) * 72 + r * 16 + (t >> 4)] = (_Float16)quant_e4m3(v.w / scale);
  }
  __syncthreads();
#pragma unroll
  for (int j = 0; j < 2; j++) {
    const int wi = j * 256 + t;
    const int dl = wi >> 3;
    const int sch = (wi & 7) * 8;
    uint4 val = *(const uint4*)(tile + dl * 72 + sch);
    *(uint4*)(v8t + (size_t)bh * (HD * S_) + (size_t)(d0 + dl) * S_ + s0 + sch) = val;
  }
}

// ---------------------------------------------------------------------------
// MFMA flash attention. Transposed formulation:
//   S^T = K . Q^T  (C-layout: col = q = lane&31 -> in-register row stats)
//   O^T = V^T . P^T (accumulated over key tiles, online softmax rescale)
// Wave owns 64 q (2 n-tiles); workgroup = 4 waves = 256 q; grid = bh*8.
// ---------------------------------------------------------------------------
__global__ __launch_bounds__(256, 1) void attn_kernel(
    const _Float16* __restrict__ q8, const _Float16* __restrict__ k8,
    const _Float16* __restrict__ v8t, const unsigned* __restrict__ mx,
    float* __restrict__ out) {
  __shared__ __align__(16) char ldsb[35840];
  _Float16* Klds  = (_Float16*)ldsb;                 // [64 keys][136]  (17408 B)
  _Float16* VTlds = (_Float16*)(ldsb + 17408);       // [128 d][72]    (18432 B)

  const int t = threadIdx.x;
  const int wave = t >> 6;
  const int lane = t & 63;
  const int l31 = lane & 31;
  const int hf = lane >> 5;

  const int qt = blockIdx.x & 7;
  const int bh = blockIdx.x >> 3;
  const int b = bh >> 4, h = bh & 15;
  const int q0 = qt * 256;

  const float qs = __uint_as_float(mx[0]) * (1.0f / 448.0f);
  const float ks = __uint_as_float(mx[1]) * (1.0f / 448.0f);
  const float vs = __uint_as_float(mx[2]) * (1.0f / 448.0f);
  const float sfac = qs * ks * 0.08838834764831843f;   // 1/sqrt(128)

  // Q fragments in registers: qf[nt][step], B-layout: Q[q=l31][d=hf*8 + step*16 + j]
  f16x8 qf[2][8];
#pragma unroll
  for (int nt = 0; nt < 2; nt++) {
    const _Float16* qp = q8 + ((size_t)(bh * S_) + q0 + wave * 64 + nt * 32 + l31) * HD + hf * 8;
#pragma unroll
    for (int st = 0; st < 8; st++)
      qf[nt][st] = *(const f16x8*)(qp + st * 16);
  }

  f32x16 acc[4][2] = {};
  float m_run[2] = {-3.0e38f, -3.0e38f};
  float l_run[2] = {0.0f, 0.0f};

  for (int kt = 0; kt < S_ / 64; kt++) {
    const int kt0 = kt * 64;
    __syncthreads();
    // stage K tile [64][136]
#pragma unroll
    for (int r = 0; r < 4; r++) {
      const int key = r * 16 + (t >> 4);
      const int dch = (t & 15) * 8;
      uint4 v = *(const uint4*)(k8 + ((size_t)(bh * S_) + kt0 + key) * HD + dch);
      *(uint4*)(Klds + key * 136 + dch) = v;
    }
    // stage V^T tile [128][72]
#pragma unroll
    for (int r = 0; r < 4; r++) {
      const int d = r * 32 + (t >> 3);
      const int sch = (t & 7) * 8;
      uint4 v = *(const uint4*)(v8t + (size_t)bh * (HD * S_) + (size_t)d * S_ + kt0 + sch);
      *(uint4*)(VTlds + d * 72 + sch) = v;
    }
    __syncthreads();

#pragma unroll
    for (int sub = 0; sub < 2; sub++) {
      const int ksub = sub * 32;
      // ---- S^T = K . Q^T ----
      f32x16 s[2] = {};
#pragma unroll
      for (int st = 0; st < 8; st++) {
        f16x8 af = *(const f16x8*)(Klds + (ksub + l31) * 136 + st * 16 + hf * 8);
        s[0] = __builtin_amdgcn_mfma_f32_32x32x16_f16(af, qf[0][st], s[0], 0, 0, 0);
        s[1] = __builtin_amdgcn_mfma_f32_32x32x16_f16(af, qf[1][st], s[1], 0, 0, 0);
      }
      // ---- online softmax + P^T fragment build ----
      f16x8 pf[2][2];
#pragma unroll
      for (int nt = 0; nt < 2; nt++) {
        float p[16];
        float tmax = -3.0e38f;
#pragma unroll
        for (int i = 0; i < 16; i++) {
          p[i] = s[nt][i] * sfac;
          tmax = fmaxf(tmax, p[i]);
        }
        tmax = fmaxf(tmax, __shfl_xor(tmax, 32));
        const float m_new = fmaxf(m_run[nt], tmax);
        const float alpha = __expf(m_run[nt] - m_new);
        m_run[nt] = m_new;
        float rs = 0.0f;
#pragma unroll
        for (int i = 0; i < 16; i++) {
          p[i] = __expf(p[i] - m_new);
          rs += p[i];
        }
        rs += __shfl_xor(rs, 32);
        l_run[nt] = l_run[nt] * alpha + rs;
#pragma unroll
        for (int dt = 0; dt < 4; dt++)
#pragma unroll
          for (int i = 0; i < 16; i++) acc[dt][nt][i] *= alpha;
        // pack + cross-half exchange -> P^T B-frags (keys ascending)
#pragma unroll
        for (int c = 0; c < 2; c++) {
          const int c8 = c * 8;
          const int sidx = hf ? 0 : 4;   // regs to send
          const int oidx = hf ? 4 : 0;   // regs to keep
          H2 s0h, s1h, o0h, o1h;
          s0h.h[0] = (_Float16)p[c8 + sidx];     s0h.h[1] = (_Float16)p[c8 + sidx + 1];
          s1h.h[0] = (_Float16)p[c8 + sidx + 2]; s1h.h[1] = (_Float16)p[c8 + sidx + 3];
          o0h.h[0] = (_Float16)p[c8 + oidx];     o0h.h[1] = (_Float16)p[c8 + oidx + 1];
          o1h.h[0] = (_Float16)p[c8 + oidx + 2]; o1h.h[1] = (_Float16)p[c8 + oidx + 3];
          unsigned r0 = (unsigned)__shfl_xor((int)s0h.u, 32);
          unsigned r1 = (unsigned)__shfl_xor((int)s1h.u, 32);
          unsigned fu[4];
          if (hf == 0) { fu[0] = o0h.u; fu[1] = o1h.u; fu[2] = r0; fu[3] = r1; }
          else         { fu[0] = r0;    fu[1] = r1;    fu[2] = o0h.u; fu[3] = o1h.u; }
          pf[nt][c] = *(f16x8*)fu;
        }
      }
      // ---- O^T += V^T . P^T ----
#pragma unroll
      for (int dt = 0; dt < 4; dt++) {
#pragma unroll
        for (int c = 0; c < 2; c++) {
          f16x8 vf = *(const f16x8*)(VTlds + (dt * 32 + l31) * 72 + ksub + c * 16 + hf * 8);
          acc[dt][0] = __builtin_amdgcn_mfma_f32_32x32x16_f16(vf, pf[0][c], acc[dt][0], 0, 0, 0);
          acc[dt][1] = __builtin_amdgcn_mfma_f32_32x32x16_f16(vf, pf[1][c], acc[dt][1], 0, 0, 0);
        }
      }
    }
  }

  // ---- epilogue: O^T -> O via per-wave LDS transpose, coalesced stores ----
  __syncthreads();
  float* scr = (float*)ldsb + wave * 1056;   // 32 x 33 fp32
#pragma unroll
  for (int dt = 0; dt < 4; dt++) {
#pragma unroll
    for (int nt = 0; nt < 2; nt++) {
      const float f = vs / l_run[nt];
#pragma unroll
      for (int i = 0; i < 16; i++) {
        const int dl = (i & 3) + 8 * (i >> 2) + 4 * hf;
        scr[dl * 33 + l31] = acc[dt][nt][i] * f;
      }
      __syncthreads();
#pragma unroll
      for (int g = 0; g < 4; g++) {
        const int idx = g * 64 + lane;
        const int ql = idx >> 3;
        const int dd = (idx & 7) * 4;
        float4 o;
        o.x = scr[(dd + 0) * 33 + ql];
        o.y = scr[(dd + 1) * 33 + ql];
        o.z = scr[(dd + 2) * 33 + ql];
        o.w = scr[(dd + 3) * 33 + ql];
        const int qg = q0 + wave * 64 + nt * 32 + ql;
        *(float4*)(out + (size_t)(b * S_ + qg) * H_ + h * HD + dt * 32 + dd) = o;
      }
      __syncthreads();
    }
  }
}

// ---------------------------------------------------------------------------
extern "C" void kernel_launch(void* const* d_in, const int* in_sizes, int n_in,
                              void* d_out, int out_size, void* d_ws, size_t ws_size,
                              hipStream_t stream) {
  const float* x     = (const float*)d_in[0];
  const float* W_qkv = (const float*)d_in[1];
  const float* W_out = (const float*)d_in[2];
  const float* b_out = (const float*)d_in[3];
  float* out = (float*)d_out;

  char* ws = (char*)d_ws;
  float* qkv        = (float*)ws;                          // 100,663,296 B
  _Float16* q8      = (_Float16*)(ws + 100663296);         // 16 MB each
  _Float16* k8      = (_Float16*)(ws + 117440512);
  _Float16* v8t     = (_Float16*)(ws + 134217728);         // transposed [bh][d][s]
  unsigned* mx      = (unsigned*)(ws + 150994944);
  float* attn_out   = (float*)ws;                          // reuse qkv region

  hipMemsetAsync(mx, 0, 3 * sizeof(unsigned), stream);

  sgemm128<<<dim3(F3 / 128, ROWS / 128), 256, 0, stream>>>(
      x, W_qkv, qkv, nullptr, ROWS, F3, H_, 0);

  maxabs_kernel<<<ROWS * 3, 256, 0, stream>>>(qkv, mx);

  quant_qk<<<(ROWS * 4096) / 1024, 256, 0, stream>>>(qkv, mx, q8, k8);
  quant_v_t<<<B_ * NH * 32 * 2, 256, 0, stream>>>(qkv, mx, v8t);

  attn_kernel<<<B_ * NH * 8, 256, 0, stream>>>(q8, k8, v8t, mx, attn_out);

  sgemm128<<<dim3(H_ / 128, ROWS / 128), 256, 0, stream>>>(
      attn_out, W_out, out, b_out, ROWS, H_, H_, 1);
}

// Round 4
// 1141.560 us; speedup vs baseline: 11.7885x; 1.9105x over previous
//
#include <hip/hip_runtime.h>
#include <hip/hip_bf16.h>
#include <math.h>

#define B_   2
#define S_   2048
#define H_   2048
#define NH   16
#define HD   128
#define ROWS (B_ * S_)   // 4096
#define F3   (3 * H_)    // 6144
#define KS   2048        // inner dim of both projection GEMMs (per split term)

typedef _Float16 f16x8 __attribute__((ext_vector_type(8)));
typedef float    f32x4  __attribute__((ext_vector_type(4)));
typedef float    f32x16 __attribute__((ext_vector_type(16)));

union H2 { unsigned u; _Float16 h[2]; };
union H4 { ushort4 s4; _Float16 h[4]; };

__device__ __forceinline__ void gl_lds16(const void* g, void* l) {
  __builtin_amdgcn_global_load_lds(
      (const __attribute__((address_space(1))) void*)g,
      (__attribute__((address_space(3))) void*)l, 16, 0, 0);
}

// ---------------------------------------------------------------------------
// fp8 e4m3fn RNE quantization -> representable value (exact in fp16)
// ---------------------------------------------------------------------------
__device__ __forceinline__ float quant_e4m3(float x) {
  float ax = fabsf(x);
  float q;
  if (ax < 0.015625f) {
    q = rintf(ax * 512.0f) * (1.0f / 512.0f);
  } else {
    unsigned eb = __float_as_uint(ax) & 0x7f800000u;
    float quantum = __uint_as_float(eb - (3u << 23));      // 2^(e-3)
    q = rintf(ax / quantum) * quantum;
    if (q > 448.0f) q = 448.0f;
  }
  return copysignf(q, x);
}

// ---------------------------------------------------------------------------
// fp32 -> fp16 hi/lo split, elementwise (for A operands: x, attn_out)
// ---------------------------------------------------------------------------
__global__ __launch_bounds__(256) void split_ab(
    const float* __restrict__ in, _Float16* __restrict__ hi,
    _Float16* __restrict__ lo) {
  const size_t i = (size_t)blockIdx.x * 256 + threadIdx.x;
  float4 v = ((const float4*)in)[i];
  H4 h, l;
  h.h[0] = (_Float16)v.x; l.h[0] = (_Float16)(v.x - (float)h.h[0]);
  h.h[1] = (_Float16)v.y; l.h[1] = (_Float16)(v.y - (float)h.h[1]);
  h.h[2] = (_Float16)v.z; l.h[2] = (_Float16)(v.z - (float)h.h[2]);
  h.h[3] = (_Float16)v.w; l.h[3] = (_Float16)(v.w - (float)h.h[3]);
  ((ushort4*)hi)[i] = h.s4;
  ((ushort4*)lo)[i] = l.s4;
}

// ---------------------------------------------------------------------------
// fp32 K x N -> fp16 hi/lo, TRANSPOSED to N x K (for B operands: W_qkv, W_out)
// 64x64 tiles through LDS.
// ---------------------------------------------------------------------------
__global__ __launch_bounds__(256) void split_tr(
    const float* __restrict__ in, _Float16* __restrict__ hi,
    _Float16* __restrict__ lo, int K, int N) {
  __shared__ _Float16 ht[64][72];   // [n][k], row = 144 B (16B-aligned)
  __shared__ _Float16 lt[64][72];
  const int t = threadIdx.x;
  const int n0 = blockIdx.x * 64, k0 = blockIdx.y * 64;
#pragma unroll
  for (int p = 0; p < 4; p++) {
    const int k = p * 16 + (t >> 4);
    const int n = (t & 15) * 4;
    float4 v = *(const float4*)(in + (size_t)(k0 + k) * N + n0 + n);
    _Float16 h0 = (_Float16)v.x, h1 = (_Float16)v.y,
             h2 = (_Float16)v.z, h3 = (_Float16)v.w;
    ht[n + 0][k] = h0; lt[n + 0][k] = (_Float16)(v.x - (float)h0);
    ht[n + 1][k] = h1; lt[n + 1][k] = (_Float16)(v.y - (float)h1);
    ht[n + 2][k] = h2; lt[n + 2][k] = (_Float16)(v.z - (float)h2);
    ht[n + 3][k] = h3; lt[n + 3][k] = (_Float16)(v.w - (float)h3);
  }
  __syncthreads();
#pragma unroll
  for (int it = 0; it < 2; it++) {
    const int idx = it * 256 + t;
    const int r = idx >> 3, c = (idx & 7) * 8;
    *(uint4*)(hi + (size_t)(n0 + r) * K + k0 + c) = *(const uint4*)&ht[r][c];
    *(uint4*)(lo + (size_t)(n0 + r) * K + k0 + c) = *(const uint4*)&lt[r][c];
  }
}

// ---------------------------------------------------------------------------
// MFMA split-fp16 GEMM: C[M,N] = A @ B^T over K' = 3*KS with phase-selected
// hi/lo operands (Ahi.Bhi + Ahi.Blo + Alo.Bhi).  A: M x KS, Bt: N x KS.
// 128x128 tile, BK=32, 256 thr, global_load_lds staging, 16x16x32 f16 MFMA.
// ---------------------------------------------------------------------------
__global__ __launch_bounds__(256) void gemm_split(
    const _Float16* __restrict__ Ahi, const _Float16* __restrict__ Alo,
    const _Float16* __restrict__ Bthi, const _Float16* __restrict__ Btlo,
    float* __restrict__ C, const float* __restrict__ bias,
    int N, int has_bias) {
  __shared__ _Float16 Asm[128 * 32];
  __shared__ _Float16 Bsm[128 * 32];
  const int t = threadIdx.x;
  const int wave = t >> 6, lane = t & 63;
  const int l15 = lane & 15, g = lane >> 4;
  const int row0 = blockIdx.y * 128, col0 = blockIdx.x * 128;
  const int wm = wave & 1, wn = wave >> 1;
  const int srow = wave * 32 + (lane >> 2);     // staging row within tile (+16 for i=1)
  const int schunk = (lane & 3) * 8;

  f32x4 acc[4][4] = {};

  for (int kc = 0; kc < 3 * (KS / 32); kc++) {
    const int phase = kc >> 6;                  // KS/32 == 64 chunks per phase
    const int klocal = (kc & 63) << 5;
    const _Float16* As = (phase == 2) ? Alo : Ahi;
    const _Float16* Bs = (phase == 1) ? Btlo : Bthi;
    __syncthreads();
#pragma unroll
    for (int i = 0; i < 2; i++) {
      gl_lds16(As + (size_t)(row0 + srow + i * 16) * KS + klocal + schunk,
               Asm + (wave * 32 + i * 16) * 32);
      gl_lds16(Bs + (size_t)(col0 + srow + i * 16) * KS + klocal + schunk,
               Bsm + (wave * 32 + i * 16) * 32);
    }
    __syncthreads();
    f16x8 af[4], bf[4];
#pragma unroll
    for (int i = 0; i < 4; i++)
      af[i] = *(const f16x8*)(Asm + (wm * 64 + i * 16 + l15) * 32 + g * 8);
#pragma unroll
    for (int j = 0; j < 4; j++)
      bf[j] = *(const f16x8*)(Bsm + (wn * 64 + j * 16 + l15) * 32 + g * 8);
#pragma unroll
    for (int i = 0; i < 4; i++)
#pragma unroll
      for (int j = 0; j < 4; j++)
        acc[i][j] = __builtin_amdgcn_mfma_f32_16x16x32_f16(af[i], bf[j], acc[i][j], 0, 0, 0);
  }

#pragma unroll
  for (int j = 0; j < 4; j++) {
    const int col = col0 + wn * 64 + j * 16 + l15;
    const float bv = has_bias ? bias[col] : 0.0f;
#pragma unroll
    for (int i = 0; i < 4; i++) {
      const int rbase = row0 + wm * 64 + i * 16 + g * 4;
#pragma unroll
      for (int r = 0; r < 4; r++)
        C[(size_t)(rbase + r) * N + col] = acc[i][j][r] + bv;
    }
  }
}

// ---------------------------------------------------------------------------
// Global max|.| per q/k/v segment
// ---------------------------------------------------------------------------
__global__ __launch_bounds__(256) void maxabs_kernel(
    const float* __restrict__ qkv, unsigned* __restrict__ mx) {
  __shared__ float red[256];
  const int seg = blockIdx.x % 3;
  const int row = blockIdx.x / 3;
  const float4* p = (const float4*)(qkv + (size_t)row * F3 + seg * 2048);
  float m = 0.0f;
  for (int i = threadIdx.x; i < 512; i += 256) {
    float4 v = p[i];
    m = fmaxf(m, fmaxf(fmaxf(fabsf(v.x), fabsf(v.y)), fmaxf(fabsf(v.z), fabsf(v.w))));
  }
  red[threadIdx.x] = m;
  __syncthreads();
  for (int s = 128; s > 0; s >>= 1) {
    if (threadIdx.x < s) red[threadIdx.x] = fmaxf(red[threadIdx.x], red[threadIdx.x + s]);
    __syncthreads();
  }
  if (threadIdx.x == 0) atomicMax(mx + seg, __float_as_uint(red[0]));
}

// ---------------------------------------------------------------------------
// Quantize Q,K segments -> fp16 exact e4m3 values, [bh][s][d]
// ---------------------------------------------------------------------------
__global__ __launch_bounds__(256) void quant_qk(
    const float* __restrict__ qkv, const unsigned* __restrict__ mx,
    _Float16* __restrict__ q8, _Float16* __restrict__ k8) {
  const size_t base = ((size_t)blockIdx.x * 256 + threadIdx.x) * 4;
  const int row = (int)(base >> 12);
  const int col = (int)(base & 4095);
  const int seg = col >> 11;
  const int c2 = col & 2047;
  const int h = c2 >> 7, d = c2 & 127;
  const int b = row >> 11, s = row & 2047;
  const float scale = __uint_as_float(mx[seg]) / 448.0f;
  float4 v = *(const float4*)(qkv + (size_t)row * F3 + col);
  H4 r;
  r.h[0] = (_Float16)quant_e4m3(v.x / scale);
  r.h[1] = (_Float16)quant_e4m3(v.y / scale);
  r.h[2] = (_Float16)quant_e4m3(v.z / scale);
  r.h[3] = (_Float16)quant_e4m3(v.w / scale);
  _Float16* dst = seg ? k8 : q8;
  const size_t di = ((size_t)((b * NH + h) * S_) + s) * HD + d;
  *(ushort4*)(dst + di) = r.s4;
}

// ---------------------------------------------------------------------------
// Quantize V -> fp16 values stored TRANSPOSED: v8t[bh][d][s]
// ---------------------------------------------------------------------------
__global__ __launch_bounds__(256) void quant_v_t(
    const float* __restrict__ qkv, const unsigned* __restrict__ mx,
    _Float16* __restrict__ v8t) {
  __shared__ _Float16 tile[64 * 72];
  const int t = threadIdx.x;
  const int bt = blockIdx.x;
  const int dtile = bt & 1;
  const int stile = (bt >> 1) & 31;
  const int bh = bt >> 6;
  const int b = bh >> 4, h = bh & 15;
  const int s0 = stile * 64, d0 = dtile * 64;
  const float scale = __uint_as_float(mx[2]) / 448.0f;

#pragma unroll
  for (int r = 0; r < 4; r++) {
    const int s = s0 + r * 16 + (t >> 4);
    const int dl = (t & 15) * 4;
    float4 v = *(const float4*)(qkv + (size_t)(b * S_ + s) * F3 + 4096 + h * HD + d0 + dl);
    tile[(dl + 0) * 72 + r * 16 + (t >> 4)] = (_Float16)quant_e4m3(v.x / scale);
    tile[(dl + 1) * 72 + r * 16 + (t >> 4)] = (_Float16)quant_e4m3(v.y / scale);
    tile[(dl + 2) * 72 + r * 16 + (t >> 4)] = (_Float16)quant_e4m3(v.z / scale);
    tile[(dl + 3) * 72 + r * 16 + (t >> 4)] = (_Float16)quant_e4m3(v.w / scale);
  }
  __syncthreads();
#pragma unroll
  for (int j = 0; j < 2; j++) {
    const int wi = j * 256 + t;
    const int dl = wi >> 3;
    const int sch = (wi & 7) * 8;
    uint4 val = *(const uint4*)(tile + dl * 72 + sch);
    *(uint4*)(v8t + (size_t)bh * (HD * S_) + (size_t)(d0 + dl) * S_ + s0 + sch) = val;
  }
}

// ---------------------------------------------------------------------------
// MFMA flash attention (unchanged from round 2).
// ---------------------------------------------------------------------------
__global__ __launch_bounds__(256, 1) void attn_kernel(
    const _Float16* __restrict__ q8, const _Float16* __restrict__ k8,
    const _Float16* __restrict__ v8t, const unsigned* __restrict__ mx,
    float* __restrict__ out) {
  __shared__ __align__(16) char ldsb[35840];
  _Float16* Klds  = (_Float16*)ldsb;                 // [64 keys][136]
  _Float16* VTlds = (_Float16*)(ldsb + 17408);       // [128 d][72]

  const int t = threadIdx.x;
  const int wave = t >> 6;
  const int lane = t & 63;
  const int l31 = lane & 31;
  const int hf = lane >> 5;

  const int qt = blockIdx.x & 7;
  const int bh = blockIdx.x >> 3;
  const int b = bh >> 4, h = bh & 15;
  const int q0 = qt * 256;

  const float qs = __uint_as_float(mx[0]) * (1.0f / 448.0f);
  const float ks = __uint_as_float(mx[1]) * (1.0f / 448.0f);
  const float vs = __uint_as_float(mx[2]) * (1.0f / 448.0f);
  const float sfac = qs * ks * 0.08838834764831843f;

  f16x8 qf[2][8];
#pragma unroll
  for (int nt = 0; nt < 2; nt++) {
    const _Float16* qp = q8 + ((size_t)(bh * S_) + q0 + wave * 64 + nt * 32 + l31) * HD + hf * 8;
#pragma unroll
    for (int st = 0; st < 8; st++)
      qf[nt][st] = *(const f16x8*)(qp + st * 16);
  }

  f32x16 acc[4][2] = {};
  float m_run[2] = {-3.0e38f, -3.0e38f};
  float l_run[2] = {0.0f, 0.0f};

  for (int kt = 0; kt < S_ / 64; kt++) {
    const int kt0 = kt * 64;
    __syncthreads();
#pragma unroll
    for (int r = 0; r < 4; r++) {
      const int key = r * 16 + (t >> 4);
      const int dch = (t & 15) * 8;
      uint4 v = *(const uint4*)(k8 + ((size_t)(bh * S_) + kt0 + key) * HD + dch);
      *(uint4*)(Klds + key * 136 + dch) = v;
    }
#pragma unroll
    for (int r = 0; r < 4; r++) {
      const int d = r * 32 + (t >> 3);
      const int sch = (t & 7) * 8;
      uint4 v = *(const uint4*)(v8t + (size_t)bh * (HD * S_) + (size_t)d * S_ + kt0 + sch);
      *(uint4*)(VTlds + d * 72 + sch) = v;
    }
    __syncthreads();

#pragma unroll
    for (int sub = 0; sub < 2; sub++) {
      const int ksub = sub * 32;
      f32x16 s[2] = {};
#pragma unroll
      for (int st = 0; st < 8; st++) {
        f16x8 af = *(const f16x8*)(Klds + (ksub + l31) * 136 + st * 16 + hf * 8);
        s[0] = __builtin_amdgcn_mfma_f32_32x32x16_f16(af, qf[0][st], s[0], 0, 0, 0);
        s[1] = __builtin_amdgcn_mfma_f32_32x32x16_f16(af, qf[1][st], s[1], 0, 0, 0);
      }
      f16x8 pf[2][2];
#pragma unroll
      for (int nt = 0; nt < 2; nt++) {
        float p[16];
        float tmax = -3.0e38f;
#pragma unroll
        for (int i = 0; i < 16; i++) {
          p[i] = s[nt][i] * sfac;
          tmax = fmaxf(tmax, p[i]);
        }
        tmax = fmaxf(tmax, __shfl_xor(tmax, 32));
        const float m_new = fmaxf(m_run[nt], tmax);
        const float alpha = __expf(m_run[nt] - m_new);
        m_run[nt] = m_new;
        float rs = 0.0f;
#pragma unroll
        for (int i = 0; i < 16; i++) {
          p[i] = __expf(p[i] - m_new);
          rs += p[i];
        }
        rs += __shfl_xor(rs, 32);
        l_run[nt] = l_run[nt] * alpha + rs;
#pragma unroll
        for (int dt = 0; dt < 4; dt++)
#pragma unroll
          for (int i = 0; i < 16; i++) acc[dt][nt][i] *= alpha;
#pragma unroll
        for (int c = 0; c < 2; c++) {
          const int c8 = c * 8;
          const int sidx = hf ? 0 : 4;
          const int oidx = hf ? 4 : 0;
          H2 s0h, s1h, o0h, o1h;
          s0h.h[0] = (_Float16)p[c8 + sidx];     s0h.h[1] = (_Float16)p[c8 + sidx + 1];
          s1h.h[0] = (_Float16)p[c8 + sidx + 2]; s1h.h[1] = (_Float16)p[c8 + sidx + 3];
          o0h.h[0] = (_Float16)p[c8 + oidx];     o0h.h[1] = (_Float16)p[c8 + oidx + 1];
          o1h.h[0] = (_Float16)p[c8 + oidx + 2]; o1h.h[1] = (_Float16)p[c8 + oidx + 3];
          unsigned r0 = (unsigned)__shfl_xor((int)s0h.u, 32);
          unsigned r1 = (unsigned)__shfl_xor((int)s1h.u, 32);
          unsigned fu[4];
          if (hf == 0) { fu[0] = o0h.u; fu[1] = o1h.u; fu[2] = r0; fu[3] = r1; }
          else         { fu[0] = r0;    fu[1] = r1;    fu[2] = o0h.u; fu[3] = o1h.u; }
          pf[nt][c] = *(f16x8*)fu;
        }
      }
#pragma unroll
      for (int dt = 0; dt < 4; dt++) {
#pragma unroll
        for (int c = 0; c < 2; c++) {
          f16x8 vf = *(const f16x8*)(VTlds + (dt * 32 + l31) * 72 + ksub + c * 16 + hf * 8);
          acc[dt][0] = __builtin_amdgcn_mfma_f32_32x32x16_f16(vf, pf[0][c], acc[dt][0], 0, 0, 0);
          acc[dt][1] = __builtin_amdgcn_mfma_f32_32x32x16_f16(vf, pf[1][c], acc[dt][1], 0, 0, 0);
        }
      }
    }
  }

  __syncthreads();
  float* scr = (float*)ldsb + wave * 1056;
#pragma unroll
  for (int dt = 0; dt < 4; dt++) {
#pragma unroll
    for (int nt = 0; nt < 2; nt++) {
      const float f = vs / l_run[nt];
#pragma unroll
      for (int i = 0; i < 16; i++) {
        const int dl = (i & 3) + 8 * (i >> 2) + 4 * hf;
        scr[dl * 33 + l31] = acc[dt][nt][i] * f;
      }
      __syncthreads();
#pragma unroll
      for (int g = 0; g < 4; g++) {
        const int idx = g * 64 + lane;
        const int ql = idx >> 3;
        const int dd = (idx & 7) * 4;
        float4 o;
        o.x = scr[(dd + 0) * 33 + ql];
        o.y = scr[(dd + 1) * 33 + ql];
        o.z = scr[(dd + 2) * 33 + ql];
        o.w = scr[(dd + 3) * 33 + ql];
        const int qg = q0 + wave * 64 + nt * 32 + ql;
        *(float4*)(out + (size_t)(b * S_ + qg) * H_ + h * HD + dt * 32 + dd) = o;
      }
      __syncthreads();
    }
  }
}

// ---------------------------------------------------------------------------
extern "C" void kernel_launch(void* const* d_in, const int* in_sizes, int n_in,
                              void* d_out, int out_size, void* d_ws, size_t ws_size,
                              hipStream_t stream) {
  const float* x     = (const float*)d_in[0];
  const float* W_qkv = (const float*)d_in[1];
  const float* W_out = (const float*)d_in[2];
  const float* b_out = (const float*)d_in[3];
  float* out = (float*)d_out;

  char* ws = (char*)d_ws;
  // Region 0 [0, 100.66 MB): qkv fp32; later attn_out + A2 splits + B2t splits
  float*    qkv    = (float*)ws;
  float*    attn_o = (float*)ws;                               // 33,554,432 B
  _Float16* A2hi   = (_Float16*)(ws + 33554432);               // 16,777,216 B
  _Float16* A2lo   = (_Float16*)(ws + 50331648);
  _Float16* B2thi  = (_Float16*)(ws + 67108864);               //  8,388,608 B
  _Float16* B2tlo  = (_Float16*)(ws + 75497472);
  // Region 1 [100.66, 151.0 MB): B1t splits, then reused for q8/k8/v8t
  _Float16* B1thi  = (_Float16*)(ws + 100663296);              // 25,165,824 B
  _Float16* B1tlo  = (_Float16*)(ws + 125829120);
  _Float16* q8     = (_Float16*)(ws + 100663296);              // 16,777,216 B
  _Float16* k8     = (_Float16*)(ws + 117440512);
  _Float16* v8t    = (_Float16*)(ws + 134217728);
  // Region 2 [151.0, 184.6 MB): A1 splits
  _Float16* A1hi   = (_Float16*)(ws + 150994944);
  _Float16* A1lo   = (_Float16*)(ws + 167772160);
  unsigned* mx     = (unsigned*)(ws + 184549376);

  hipMemsetAsync(mx, 0, 3 * sizeof(unsigned), stream);

  // split x (A1) and W_qkv^T (B1t)
  split_ab<<<(ROWS * H_) / 1024, 256, 0, stream>>>(x, A1hi, A1lo);
  split_tr<<<dim3(F3 / 64, H_ / 64), 256, 0, stream>>>(W_qkv, B1thi, B1tlo, H_, F3);

  // qkv = x @ W_qkv  (split-fp16 MFMA, K' = 6144)
  gemm_split<<<dim3(F3 / 128, ROWS / 128), 256, 0, stream>>>(
      A1hi, A1lo, B1thi, B1tlo, qkv, nullptr, F3, 0);

  maxabs_kernel<<<ROWS * 3, 256, 0, stream>>>(qkv, mx);
  quant_qk<<<(ROWS * 4096) / 1024, 256, 0, stream>>>(qkv, mx, q8, k8);
  quant_v_t<<<B_ * NH * 32 * 2, 256, 0, stream>>>(qkv, mx, v8t);

  attn_kernel<<<B_ * NH * 8, 256, 0, stream>>>(q8, k8, v8t, mx, attn_o);

  // split attn_out (A2) and W_out^T (B2t)
  split_ab<<<(ROWS * H_) / 1024, 256, 0, stream>>>(attn_o, A2hi, A2lo);
  split_tr<<<dim3(H_ / 64, H_ / 64), 256, 0, stream>>>(W_out, B2thi, B2tlo, H_, H_);

  // out = attn_out @ W_out + b_out
  gemm_split<<<dim3(H_ / 128, ROWS / 128), 256, 0, stream>>>(
      A2hi, A2lo, B2thi, B2tlo, out, b_out, H_, 1);
}